// Round 5
// baseline (7334.488 us; speedup 1.0000x reference)
//
#include <hip/hip_runtime.h>
#include <hip/hip_bf16.h>

// Problem constants
#define T_LEN 2048
#define E_DIM 300
#define H_DIM 512
#define G_DIM 2048   // 4*H
#define NBLK  32     // blocks per (direction,sentence) chain in recurrent kernel
#define UPB   16     // hidden units per block (H/NBLK)
#define TAG_OFF 0x40000000u

// Workspace layout (bytes).
// hb: (value,tag) pairs [2 dir][2 parity][2 sent][512] u64 = 16 KB
#define WS_H   0
#define WS_X   16384       // x: [2 sent][2048][300] f32 = 4,915,200 B
#define WS_GX  5242880     // gx: [d*2+s][2048 t][32 bb][4 q][16 ul] bf16 = 33,554,432 B

typedef float v2f __attribute__((ext_vector_type(2)));

__device__ __forceinline__ float sigmoid_fast(float x) {
    return 1.f / (1.f + __expf(-x));
}
__device__ __forceinline__ float tanh_fast(float x) {
    x = fminf(fmaxf(x, -15.f), 15.f);
    float e = __expf(-2.f * x);
    return (1.f - e) / (1.f + e);
}

// ---------------- k1: embedding gather ----------------
__global__ void k_gather(const int* __restrict__ sentA, const int* __restrict__ sentB,
                         const float* __restrict__ emb, float* __restrict__ x) {
    const int s = blockIdx.y;
    const int* sent = s ? sentB : sentA;
    const int t0 = blockIdx.x * 16;
    for (int idx = threadIdx.x; idx < 16 * 300; idx += 256) {
        int r = idx / 300, e = idx - r * 300;
        int t = t0 + r;
        int row = sent[t];
        x[((size_t)(s * 2048 + t)) * 300 + e] = emb[(size_t)row * 300 + e];
    }
}

// ---------------- k2: gx = x @ w_ih^T + (b_ih + b_hh), bf16, block-sliced layout ----------------
// grid (32 gi, 64 ti, 4 = d*2+s), block 256. Both tiles staged in LDS
// (coalesced global loads); K chunked 3x100.
__global__ __launch_bounds__(256) void k_gemm(const float* __restrict__ x,
                                              const float* __restrict__ w_ih,
                                              const float* __restrict__ b_ih,
                                              const float* __restrict__ b_hh,
                                              __hip_bfloat16* __restrict__ gx) {
    // stride 108 floats (432B, 16B-aligned rows; 108 mod 32 = 12 -> <=2-way banks)
    __shared__ float xs[32 * 108];
    __shared__ float ws_[64 * 108];
    const int gi = blockIdx.x, ti = blockIdx.y, z = blockIdx.z;
    const int d = z >> 1, s = z & 1;
    const int t0 = ti * 32, g0 = gi * 64;
    const int tg = threadIdx.x & 15, tt = threadIdx.x >> 4;
    const float* wbase = w_ih + (size_t)d * G_DIM * E_DIM;

    float acc[2][4];
#pragma unroll
    for (int j = 0; j < 2; ++j)
#pragma unroll
        for (int i = 0; i < 4; ++i) acc[j][i] = 0.f;

    for (int e0 = 0; e0 < 300; e0 += 100) {
        // stage x tile: 32 rows x 25 float4
        for (int idx = threadIdx.x; idx < 32 * 25; idx += 256) {
            int r = idx / 25, c = idx - r * 25;
            float4 v = *(const float4*)(x + ((size_t)(s * 2048 + t0 + r)) * 300 + e0 + c * 4);
            *(float4*)&xs[r * 108 + c * 4] = v;
        }
        // stage w tile: 64 rows x 25 float4
        for (int idx = threadIdx.x; idx < 64 * 25; idx += 256) {
            int r = idx / 25, c = idx - r * 25;
            float4 v = *(const float4*)(wbase + (size_t)(g0 + r) * 300 + e0 + c * 4);
            *(float4*)&ws_[r * 108 + c * 4] = v;
        }
        __syncthreads();

        for (int c = 0; c < 25; ++c) {
            float4 xv[2], wv[4];
#pragma unroll
            for (int j = 0; j < 2; ++j) xv[j] = *(const float4*)&xs[(tt + 16 * j) * 108 + c * 4];
#pragma unroll
            for (int i = 0; i < 4; ++i) wv[i] = *(const float4*)&ws_[(tg + 16 * i) * 108 + c * 4];
#pragma unroll
            for (int j = 0; j < 2; ++j)
#pragma unroll
                for (int i = 0; i < 4; ++i)
                    acc[j][i] += xv[j].x * wv[i].x + xv[j].y * wv[i].y +
                                 xv[j].z * wv[i].z + xv[j].w * wv[i].w;
        }
        __syncthreads();
    }

#pragma unroll
    for (int i = 0; i < 4; ++i) {
        int g = g0 + tg + 16 * i;
        float bias = b_ih[d * G_DIM + g] + b_hh[d * G_DIM + g];
        // block-sliced position: [bb][q][ul]
        int pos = ((g >> 4) & 31) * 64 + (g >> 9) * 16 + (g & 15);
#pragma unroll
        for (int j = 0; j < 2; ++j) {
            int t = t0 + tt + 16 * j;
            int tout = d ? (T_LEN - 1 - t) : t;   // backward run: time-reversed rows
            float v = acc[j][i] + bias;
            gx[(((size_t)(d * 2 + s) * T_LEN + tout) << 11) + pos] = __float2bfloat16(v);
        }
    }
}

// ---------------- k3: recurrent LSTM, 128 blocks = (2 dir x 2 sent x 32), BARRIER-FREE ----------------
// One block per chain-slice: 16 hidden units x 4 gates of ONE (dir,sent)
// chain. h exchanged as (u32 step tag | fp32 value) u64 agent-scope atomics,
// single copy per chain (R1 scheme; publish = 16 contiguous u64/block).
// NEW: each WAVE owns complete rows (4 units x 4 gates; k split 16-way
// within the wave: lane = ul2*16 + ks, 32 k per lane per row). Each wave
// polls the FULL 512-entry h (8 u64/lane, ping-pong), stages into its
// PRIVATE parity-double-buffered LDS copy (intra-wave lgkmcnt ordering
// only -> NO __syncthreads anywhere in the loop), k-reduces via 4-stage
// shfl_xor butterfly within 16-lane groups -> every lane ends with its
// unit's complete i,f,g,o. No pacc, no B1/B2, no gate-gather.
// LDS staging is XOR-swizzled at float4 granularity (L ^= (L>>3)&7):
// naive layout would be a 16-way read bank conflict, swizzled is ~2-way.
__global__ __launch_bounds__(256, 1) void k_rnn(const float* __restrict__ w_hh,
                                                const __hip_bfloat16* __restrict__ gx,
                                                unsigned long long* __restrict__ hb) {
    const int tid  = threadIdx.x;
    const int lane = tid & 63;
    const int w    = tid >> 6;          // wave 0..3
    const int ul2  = lane >> 4;         // unit within wave, 0..3
    const int ks   = lane & 15;         // k-split 0..15 (32 k each)
    const int bid = blockIdx.x;         // (d*2+s)*32 + bb
    const int d  = bid >> 6;
    const int s  = (bid >> 5) & 1;
    const int bb = bid & 31;
    const int cs = d * 2 + s;           // chain index 0..3
    const int ul = w * 4 + ul2;         // local unit 0..15
    const int gu = bb * 16 + ul;        // global unit 0..511

    // persistent weights: wv2[q][j] = { W[q*512+gu][ks*32+2j], W[..][ks*32+2j+1] }
    v2f wv2[4][16];
#pragma unroll
    for (int q = 0; q < 4; ++q) {
        const float* wp = w_hh + ((size_t)d * G_DIM + q * 512 + gu) * H_DIM + ks * 32;
#pragma unroll
        for (int j = 0; j < 16; ++j)
            wv2[q][j] = *(const v2f*)(wp + 2 * j);
    }

    // per-wave private h staging, double-buffered by parity (4 waves x 2 x 512 f32 = 16 KB)
    __shared__ float hw[4][2][512];

    float c_state = 0.f;

    // h_0 = 0, tag TAG_OFF, parity 0: each block publishes its own 16 units
    if (tid < 16) {
        __hip_atomic_store(&hb[((size_t)(d * 2 + 0) * 2 + s) * H_DIM + bb * UPB + tid],
                           (unsigned long long)TAG_OFF << 32,
                           __ATOMIC_RELAXED, __HIP_MEMORY_SCOPE_AGENT);
    }

    for (int t = 0; t < T_LEN; ++t) {
        const int p  = t & 1;
        const int pn = p ^ 1;

        // prefetch this lane's 4 gate inputs (unit ul, gates 0..3; overlaps the poll)
        float gxq[4];
        {
            const __hip_bfloat16* gp = gx + (((size_t)cs * T_LEN + t) << 11) + bb * 64 + ul;
#pragma unroll
            for (int q = 0; q < 4; ++q) gxq[q] = (float)gp[q * 16];
        }

        unsigned long long* hbp = hb + ((size_t)(d * 2 + p) * 2 + s) * H_DIM;
        const unsigned int tag = TAG_OFF + (unsigned int)t;
        unsigned long long a[8], b[8];

#define LD8(A) _Pragma("unroll") for (int jj = 0; jj < 8; ++jj) \
            A[jj] = __hip_atomic_load(&hbp[64 * jj + lane], __ATOMIC_RELAXED, __HIP_MEMORY_SCOPE_AGENT);
#define OK8(A) (((unsigned int)(A[0] >> 32) == tag) & ((unsigned int)(A[1] >> 32) == tag) & \
                ((unsigned int)(A[2] >> 32) == tag) & ((unsigned int)(A[3] >> 32) == tag) & \
                ((unsigned int)(A[4] >> 32) == tag) & ((unsigned int)(A[5] >> 32) == tag) & \
                ((unsigned int)(A[6] >> 32) == tag) & ((unsigned int)(A[7] >> 32) == tag))
        // ping-pong poll over the FULL h region: two independent 8-reg sets
        LD8(a)
        int guard = 0;
        for (;;) {
            LD8(b)
            if (__all(OK8(a))) break;
            if (++guard > (1 << 20)) break;
            LD8(a)
            if (__all(OK8(b))) {
#pragma unroll
                for (int jj = 0; jj < 8; ++jj) a[jj] = b[jj];
                break;
            }
            if (++guard > (1 << 20)) break;
        }
#undef LD8
#undef OK8

        // stage into THIS WAVE's private LDS copy, XOR-swizzled at float4 level.
        // Intra-wave ds_write -> ds_read ordering via lgkmcnt (compiler-inserted);
        // no cross-wave sharing -> no barrier.
        float* hwp = &hw[w][p][0];
#pragma unroll
        for (int jj = 0; jj < 8; ++jj) {
            int e = 64 * jj + lane;
            int L = e >> 2, sub = e & 3;
            int Lp = L ^ ((L >> 3) & 7);
            hwp[Lp * 4 + sub] = __uint_as_float((unsigned int)a[jj]);
        }

        // matvec: 4 gate-rows of unit ul, k in [ks*32, ks*32+32)
        v2f acc2[4];
#pragma unroll
        for (int q = 0; q < 4; ++q) acc2[q] = (v2f)(0.f);
#pragma unroll
        for (int jj = 0; jj < 8; ++jj) {
            int Lp = (ks * 8 + jj) ^ (ks & 7);
            float4 h4 = *(const float4*)&hwp[Lp * 4];
            v2f h2a; h2a.x = h4.x; h2a.y = h4.y;
            v2f h2b; h2b.x = h4.z; h2b.y = h4.w;
#pragma unroll
            for (int q = 0; q < 4; ++q)
                acc2[q] += wv2[q][2 * jj] * h2a + wv2[q][2 * jj + 1] * h2b;
        }

        // k-reduce: butterfly over the 16-lane ks group; afterwards ALL 16
        // lanes of the unit group hold identical full sums for all 4 gates.
        float vq[4];
#pragma unroll
        for (int q = 0; q < 4; ++q) vq[q] = acc2[q].x + acc2[q].y;
#pragma unroll
        for (int m = 1; m < 16; m <<= 1)
#pragma unroll
            for (int q = 0; q < 4; ++q) vq[q] += __shfl_xor(vq[q], m, 64);

        float i_ = sigmoid_fast(vq[0] + gxq[0]);
        float f_ = sigmoid_fast(vq[1] + gxq[1]);
        float g_ = tanh_fast(vq[2] + gxq[2]);
        float o_ = sigmoid_fast(vq[3] + gxq[3]);

        // state update in all 16 lanes (redundant, deterministic: identical
        // post-butterfly values in identical order)
        c_state = f_ * c_state + i_ * g_;
        float h_new = o_ * tanh_fast(c_state);
        unsigned long long pkt = ((unsigned long long)(TAG_OFF + (unsigned int)(t + 1)) << 32)
                               | (unsigned long long)__float_as_uint(h_new);
        if (ks == 0) {
            __hip_atomic_store(&hb[((size_t)(d * 2 + pn) * 2 + s) * H_DIM + gu],
                               pkt, __ATOMIC_RELAXED, __HIP_MEMORY_SCOPE_AGENT);
        }
        // hw WAR across steps: parity double-buffer; within a parity, the
        // wave's own program order (write t+2 after reads of t) + lgkmcnt
        // ordering protects it. hb slot WAR: poll invariant (a producer can
        // only reach step t+1's store after all blocks passed step t's poll).
    }
}

// ---------------- k4: head ----------------
__global__ __launch_bounds__(512) void k_head(const unsigned long long* __restrict__ hb,
                                              const float* __restrict__ bi_w,
                                              const float* __restrict__ bi_b,
                                              const float* __restrict__ blA,
                                              const float* __restrict__ blB,
                                              const float* __restrict__ bl_b,
                                              const float* __restrict__ out_w,
                                              const float* __restrict__ out_b,
                                              float* __restrict__ out) {
    __shared__ float enc[2][512];
    __shared__ float red[8];
    const int tid = threadIdx.x;
    const float bw0 = bi_w[0], bw1 = bi_w[1], bib = bi_b[0];
    {
        int u = tid;
        // final h (t=2048) lives in parity 0
        float hfA = __uint_as_float((unsigned int)hb[((0 * 2 + 0) * 2 + 0) * 512 + u]);
        float hbA = __uint_as_float((unsigned int)hb[((1 * 2 + 0) * 2 + 0) * 512 + u]);
        float hfB = __uint_as_float((unsigned int)hb[((0 * 2 + 0) * 2 + 1) * 512 + u]);
        float hbB = __uint_as_float((unsigned int)hb[((1 * 2 + 0) * 2 + 1) * 512 + u]);
        enc[0][u] = bw0 * hfA + bw1 * hbA + bib;
        enc[1][u] = bw0 * hfB + bw1 * hbB + bib;
    }
    __syncthreads();
    const int j = tid;
    float acc = bl_b[j];
#pragma unroll 4
    for (int u = 0; u < 512; ++u)
        acc += enc[0][u] * blA[u * 512 + j] + enc[1][u] * blB[u * 512 + j];
    float contrib = tanh_fast(acc) * out_w[j];
#pragma unroll
    for (int m = 1; m < 64; m <<= 1) contrib += __shfl_xor(contrib, m, 64);
    if ((tid & 63) == 0) red[tid >> 6] = contrib;
    __syncthreads();
    if (tid == 0) {
        float s = 0.f;
#pragma unroll
        for (int i = 0; i < 8; ++i) s += red[i];
        s += out_b[0];
        out[0] = sigmoid_fast(s);
    }
}

extern "C" void kernel_launch(void* const* d_in, const int* in_sizes, int n_in,
                              void* d_out, int out_size, void* d_ws, size_t ws_size,
                              hipStream_t stream) {
    const int*   sentA = (const int*)d_in[0];
    const int*   sentB = (const int*)d_in[1];
    // d_in[2] = hidden (unused by forward)
    const float* emb   = (const float*)d_in[3];
    const float* w_ih  = (const float*)d_in[4];
    const float* w_hh  = (const float*)d_in[5];
    const float* b_ih  = (const float*)d_in[6];
    const float* b_hh  = (const float*)d_in[7];
    const float* bi_w  = (const float*)d_in[8];
    const float* bi_b  = (const float*)d_in[9];
    const float* blA   = (const float*)d_in[10];
    const float* blB   = (const float*)d_in[11];
    const float* bl_b  = (const float*)d_in[12];
    const float* out_w = (const float*)d_in[13];
    const float* out_b = (const float*)d_in[14];
    float* out = (float*)d_out;

    char* ws = (char*)d_ws;
    unsigned long long* hbf = (unsigned long long*)(ws + WS_H);
    float*              x   = (float*)(ws + WS_X);
    __hip_bfloat16*     gx  = (__hip_bfloat16*)(ws + WS_GX);

    k_gather<<<dim3(128, 2), 256, 0, stream>>>(sentA, sentB, emb, x);
    k_gemm<<<dim3(32, 64, 4), 256, 0, stream>>>(x, w_ih, b_ih, b_hh, gx);
    k_rnn<<<dim3(128), 256, 0, stream>>>(w_hh, gx, hbf);
    k_head<<<dim3(1), 512, 0, stream>>>(hbf, bi_w, bi_b, blA, blB, bl_b, out_w, out_b, out);
}